// Round 6
// baseline (177.977 us; speedup 1.0000x reference)
//
#include <hip/hip_runtime.h>

#define HDIM 20
#define BLOCK 128

typedef __fp16 half8 __attribute__((ext_vector_type(8)));
typedef __fp16 half2v __attribute__((ext_vector_type(2)));
typedef float  float4v __attribute__((ext_vector_type(4)));
typedef int    int4v  __attribute__((ext_vector_type(4)));

static __device__ __forceinline__ float4v mfma16(half8 a, half8 b, float4v c) {
    return __builtin_amdgcn_mfma_f32_16x16x32_f16(a, b, c, 0, 0, 0);
}
static __device__ __forceinline__ int pkrtz(float a, float b) {
    return __builtin_bit_cast(int, __builtin_amdgcn_cvt_pkrtz(a, b));
}

// KEY INVARIANT (unchanged from v2):
//   B-row permutation: k = 8q + i  <->  hidden unit 4i + q   (i<5; i=5,6 pad; k=7(q=0) bias=1).
//   C/D layout (m89): lane (q,el) holds D rows 4q..4q+3 of column el.
//   Tile T rows: row 4q'+g = unit 4T+q', gate g in {r,z,nI,nH} -> lane (q,el)
//   computes h_new for unit 4T+q of col el. A rows pre-scaled: r,z by -log2e;
//   nI,nH by +2log2e (tanh via 1-2/(1+exp2)).
//
// v7: WAVE-SPLIT UNITS -> 4 waves/SIMD. After 4 scheduling nulls (v2 store
// pipeline +4%, v3 dual-stream -24%, v4 trans-cut 0%, v5 stage-ILP 0%, v6
// stagger 0%), the only untested axis is resident-wave count (pinned at
// 2/SIMD by 16 els/wave). Block = 128 thr = 2 waves sharing one 16-element
// group: wave0 owns tiles 0,1 + y-MFMA + store; wave1 owns tiles 2,3,4.
// Per step each wave packs its OWN Bf words (same fp16 bits as v2) and
// exchanges the missing words via double-buffered LDS + 1 barrier/step.
// 2048 blocks x 2 waves = 4096 waves = 4/SIMD; instr/wave drops ~80 -> ~50.

template<int NT, int T0, bool W0>
static __device__ __forceinline__ void run_role(
    const float* __restrict__ w_ih, const float* __restrict__ w_hh,
    const float* __restrict__ b_ih, const float* __restrict__ b_hh,
    const float* __restrict__ w_l,  const float* __restrict__ b_l,
    const float* __restrict__ hb, float* __restrict__ outp,
    int step, int el, int q, int l, float* xb)
{
    const float NL2E  = -1.4426950408889634f;   // r,z scale
    const float T2L2E =  2.8853900817779268f;   // n scale
    const int u_dst = el >> 2;
    const int g     = el & 3;

    // ---- A fragments for OWN tiles only ----
    half8 Afold[NT], Azero[NT], Ay;
    #pragma unroll
    for (int i = 0; i < NT; ++i) {
        const int T  = T0 + i;
        const int u  = 4 * T + u_dst;
        const int rr = (g == 0) ? u : (g == 1) ? 20 + u : 40 + u;
        const float sc = (g <= 1) ? NL2E : T2L2E;
        half8 hf, h0;
        #pragma unroll
        for (int j = 0; j < 8; ++j) {
            float af = 0.f, a0 = 0.f;
            if (j < 5) {
                const int uk = 4 * j + q;                 // permuted source unit
                float wx = w_ih[rr * 2 + 0] * w_l[uk] + w_ih[rr * 2 + 1] * w_l[HDIM + uk];
                float wh = w_hh[rr * HDIM + uk];
                if (g <= 1)      { af = wh + wx; a0 = wh; }
                else if (g == 2) { af = wx;      a0 = 0.f; }
                else             { af = wh;      a0 = wh; }
            } else if (j == 7 && q == 0) {                // bias column
                float bx = w_ih[rr * 2 + 0] * b_l[0] + w_ih[rr * 2 + 1] * b_l[1];
                if (g <= 1)      { af = b_ih[rr] + b_hh[rr] + bx; a0 = b_ih[rr] + b_hh[rr]; }
                else if (g == 2) { af = b_ih[rr] + bx;            a0 = b_ih[rr]; }
                else             { af = b_hh[rr];                 a0 = b_hh[rr]; }
            }
            hf[j] = (__fp16)(af * sc);
            h0[j] = (__fp16)(a0 * sc);
        }
        Afold[i] = hf;
        Azero[i] = h0;
    }
    if constexpr (W0) {   // y tile (unscaled)
        half8 hy;
        #pragma unroll
        for (int j = 0; j < 8; ++j) {
            float v = 0.f;
            if (el < 2) {
                if (j < 5)                 v = w_l[el * HDIM + 4 * j + q];
                else if (j == 7 && q == 0) v = b_l[el];
            }
            hy[j] = (__fp16)v;
        }
        Ay = hy;
    }

    int w3const;
    {
        half2v c67; c67[0] = (__fp16)0.f; c67[1] = (__fp16)((q == 0) ? 1.f : 0.f);
        w3const = __builtin_bit_cast(int, c67);
    }

    // own fp32 state + full initial Bf straight from global
    float hp[NT];
    #pragma unroll
    for (int i = 0; i < NT; ++i) hp[i] = hb[4 * (T0 + i) + q];

    half8 Bf;
    {
        int4v bi;
        bi[0] = pkrtz(hb[q],      hb[4 + q]);
        bi[1] = pkrtz(hb[8 + q],  hb[12 + q]);
        bi[2] = pkrtz(hb[16 + q], 0.f);
        bi[3] = w3const;
        Bf = __builtin_bit_cast(half8, bi);
    }

    const float4v czero = {0.f, 0.f, 0.f, 0.f};
    int p = 0;   // double-buffer parity

    auto do_step = [&](const half8* A, int ydst, bool do_y) {
        float4v C[NT];
        #pragma unroll
        for (int i = 0; i < NT; ++i) C[i] = mfma16(A[i], Bf, czero);
        float4v cy = czero;
        if constexpr (W0) cy = mfma16(Ay, Bf, czero);   // y of current h

        #pragma unroll
        for (int i = 0; i < NT; ++i) {
            // C = (-log2e*ar, -log2e*az, 2log2e*anI, 2log2e*anH)
            float r = __builtin_amdgcn_rcpf(1.f + __builtin_amdgcn_exp2f(C[i][0]));
            float z = __builtin_amdgcn_rcpf(1.f + __builtin_amdgcn_exp2f(C[i][1]));
            float npre2 = __builtin_fmaf(r, C[i][3], C[i][2]);
            float tn = __builtin_amdgcn_rcpf(1.f + __builtin_amdgcn_exp2f(npre2));
            float n = __builtin_fmaf(-2.f, tn, 1.f);
            hp[i] = __builtin_fmaf(z, hp[i] - n, n);    // (1-z)*n + z*h
        }

        // pack own Bf words (same bits v2 produced locally), exchange the rest
        int wA = 0, wB = 0;
        if constexpr (W0) {
            wA = pkrtz(hp[0], hp[1]);                   // word0: units q, 4+q
            xb[(p * 3 + 0) * 64 + l] = __builtin_bit_cast(float, wA);
        } else {
            wA = pkrtz(hp[0], hp[1]);                   // word1: units 8+q, 12+q
            wB = pkrtz(hp[2], 0.f);                     // word2: unit 16+q
            xb[(p * 3 + 1) * 64 + l] = __builtin_bit_cast(float, wA);
            xb[(p * 3 + 2) * 64 + l] = __builtin_bit_cast(float, wB);
        }
        __syncthreads();
        int4v bi;
        if constexpr (W0) {
            bi[0] = wA;
            bi[1] = __builtin_bit_cast(int, xb[(p * 3 + 1) * 64 + l]);
            bi[2] = __builtin_bit_cast(int, xb[(p * 3 + 2) * 64 + l]);
        } else {
            bi[0] = __builtin_bit_cast(int, xb[(p * 3 + 0) * 64 + l]);
            bi[1] = wA;
            bi[2] = wB;
        }
        bi[3] = w3const;
        Bf = __builtin_bit_cast(half8, bi);
        p ^= 1;

        if constexpr (W0) {
            if (do_y && q == 0) {                        // store after barrier: cy long done
                float2 st; st.x = cy[0]; st.y = cy[1];
                *(float2*)(outp + 2 * ydst) = st;
            }
        }
    };

    do_step(Azero, 0, false);                            // h_0 -> h_1 (x=0 step)
    for (int t = 1; t < step; ++t)
        do_step(Afold, step - t, true);                  // y_t at reversed idx

    if constexpr (W0) {                                  // final y from h_step
        float4v cy = mfma16(Ay, Bf, czero);
        if (q == 0) {
            float2 st; st.x = cy[0]; st.y = cy[1];
            *(float2*)outp = st;
        }
    }
}

__global__ __launch_bounds__(BLOCK, 4) void gru_decoder_kernel(
    const float* __restrict__ hidden,
    const float* __restrict__ w_ih,
    const float* __restrict__ w_hh,
    const float* __restrict__ b_ih,
    const float* __restrict__ b_hh,
    const float* __restrict__ w_l,
    const float* __restrict__ b_l,
    const int*  __restrict__ step_ptr,
    float* __restrict__ out,
    int B)
{
    __shared__ float xbuf[2 * 3 * 64];                   // double-buffered exchange, 1.5 KB
    const int tid = threadIdx.x;
    const int l   = tid & 63;
    const int wv  = tid >> 6;                            // wave role 0/1
    const int el  = l & 15;
    const int q   = l >> 4;
    const int e   = blockIdx.x * 16 + el;
    const int step = *step_ptr;

    const float* hb = hidden + (size_t)e * HDIM;
    float* outp = out + (size_t)e * 2 * step;

    if (wv == 0)
        run_role<2, 0, true >(w_ih, w_hh, b_ih, b_hh, w_l, b_l, hb, outp, step, el, q, l, xbuf);
    else
        run_role<3, 2, false>(w_ih, w_hh, b_ih, b_hh, w_l, b_l, hb, outp, step, el, q, l, xbuf);
}

extern "C" void kernel_launch(void* const* d_in, const int* in_sizes, int n_in,
                              void* d_out, int out_size, void* d_ws, size_t ws_size,
                              hipStream_t stream) {
    const float* hidden = (const float*)d_in[0];
    const float* w_ih   = (const float*)d_in[1];
    const float* w_hh   = (const float*)d_in[2];
    const float* b_ih   = (const float*)d_in[3];
    const float* b_hh   = (const float*)d_in[4];
    const float* w_l    = (const float*)d_in[5];
    const float* b_l    = (const float*)d_in[6];
    const int*   step   = (const int*)d_in[7];
    float* out = (float*)d_out;

    int B = in_sizes[0] / HDIM;     // hidden is (1, B, 20); B = 32768
    int grid = B / 16;              // 2 waves/block share one 16-element group

    gru_decoder_kernel<<<grid, BLOCK, 0, stream>>>(
        hidden, w_ih, w_hh, b_ih, b_hh, w_l, b_l, step, out, B);
}

// Round 7
// 162.870 us; speedup vs baseline: 1.0927x; 1.0927x over previous
//
#include <hip/hip_runtime.h>

#define HDIM 20
#define BLOCK 256

typedef __fp16 half8 __attribute__((ext_vector_type(8)));
typedef __fp16 half2v __attribute__((ext_vector_type(2)));
typedef float  float4v __attribute__((ext_vector_type(4)));
typedef int    int4v  __attribute__((ext_vector_type(4)));

static __device__ __forceinline__ float4v mfma16(half8 a, half8 b, float4v c) {
    return __builtin_amdgcn_mfma_f32_16x16x32_f16(a, b, c, 0, 0, 0);
}

// KEY INVARIANT (unchanged since v2):
//   B-row permutation: k = 8q + i  <->  hidden unit 4i + q   (i<5; i=5,6 pad; k=7(q=0) bias=1).
//   C/D layout (m89): lane (q,el) holds D rows 4q..4q+3 of column el.
//   A rows arranged so tile T, row 4q'+g = unit 4T+q', gate type g in {r,z,nI,nH}
//   -> lane (q,el) computes h_new for units {4T+q}, which are EXACTLY its own
//      B rows k=8q+T. The "allgather" is the identity: pack own h to fp16, done.
//
// v8: TRANS -> LDS LUT. Issue-cycle model (fits v2/v3/v7 within 5-10%):
// duration = per-SIMD issue cycles; trans = 16 cyc/wave64 op -> 30 trans/step
// = 960 of 1229 cyc/SIMD-step (78%). LDS pipe is idle, so replace all 15
// sigmoid/tanh evaluations with nearest-entry lookups in two 8192-entry f32
// tables over [-8,8] (step 1/512):
//   - A gate-rows pre-scaled by 512 -> MFMA emits table indices directly;
//   - +4096.5 (center + round-to-nearest) folded into the MFMA C-input;
//   - per nonlinearity: max,min,cvt,addr + ds_read_b32 (~16 cyc) vs
//     exp2+add+rcp (~34 cyc).
// LUT error <= 2.4e-4 (sigmoid) / 9.8e-4 (tanh); contractive recurrence
// keeps accumulation ~1e-3, ~fp16 state-noise order. 64 KB LDS, 2 blocks/CU.

__global__ __launch_bounds__(BLOCK, 2) void gru_decoder_kernel(
    const float* __restrict__ hidden,
    const float* __restrict__ w_ih,
    const float* __restrict__ w_hh,
    const float* __restrict__ b_ih,
    const float* __restrict__ b_hh,
    const float* __restrict__ w_l,
    const float* __restrict__ b_l,
    const int*  __restrict__ step_ptr,
    float* __restrict__ out,
    int B)
{
    __shared__ float lutS[8192];   // sigmoid(x), x = (i-4096)/512, i in [0,8192)
    __shared__ float lutT[8192];   // tanh(x)

    const int tid = threadIdx.x;

    // ---- build LUTs (once per block, ~1 us; rcp/exp2 = same primitives the
    // old per-step path used, so table values match old numerics to ~1e-7) ----
    for (int i = tid; i < 8192; i += BLOCK) {
        float x = (i - 4096) * (1.0f / 512.0f);
        float es = __builtin_amdgcn_exp2f(-1.4426950408889634f * x);
        lutS[i] = __builtin_amdgcn_rcpf(1.f + es);                          // sigmoid(x)
        float et = __builtin_amdgcn_exp2f(2.8853900817779268f * x);
        lutT[i] = __builtin_fmaf(-2.f, __builtin_amdgcn_rcpf(1.f + et), 1.f); // tanh(x)
    }
    __syncthreads();

    const int l   = tid & 63;
    const int wv  = tid >> 6;
    const int el  = l & 15;
    const int q   = l >> 4;
    const int e   = (blockIdx.x * 4 + wv) * 16 + el;
    const int step = *step_ptr;

    const float ISCALE = 512.0f;                // index units per preactivation unit

    // ---- A fragments (once). Lane holds k=8q..8q+7; A row m=el of tile T is
    // unit 4T+(el>>2), gate type el&3 {0:r,1:z,2:nI,3:nH}. All gate rows
    // pre-scaled by ISCALE so MFMA output is in LUT-index units. ----
    const int u_dst = el >> 2;
    const int g     = el & 3;

    half8 Afold[5], Azero[5], Ay;
    #pragma unroll
    for (int T = 0; T < 5; ++T) {
        const int u  = 4 * T + u_dst;
        const int rr = (g == 0) ? u : (g == 1) ? 20 + u : 40 + u;
        half8 hf, h0;
        #pragma unroll
        for (int j = 0; j < 8; ++j) {
            float af = 0.f, a0 = 0.f;
            if (j < 5) {
                const int uk = 4 * j + q;                 // permuted source unit
                float wx = w_ih[rr * 2 + 0] * w_l[uk] + w_ih[rr * 2 + 1] * w_l[HDIM + uk];
                float wh = w_hh[rr * HDIM + uk];
                if (g <= 1)      { af = wh + wx; a0 = wh; }
                else if (g == 2) { af = wx;      a0 = 0.f; }
                else             { af = wh;      a0 = wh; }
            } else if (j == 7 && q == 0) {                // bias column
                float bx = w_ih[rr * 2 + 0] * b_l[0] + w_ih[rr * 2 + 1] * b_l[1];
                if (g <= 1)      { af = b_ih[rr] + b_hh[rr] + bx; a0 = b_ih[rr] + b_hh[rr]; }
                else if (g == 2) { af = b_ih[rr] + bx;            a0 = b_ih[rr]; }
                else             { af = b_hh[rr];                 a0 = b_hh[rr]; }
            }
            hf[j] = (__fp16)(af * ISCALE);
            h0[j] = (__fp16)(a0 * ISCALE);
        }
        Afold[T] = hf;
        Azero[T] = h0;
    }
    {   // y tile (unscaled): row 0 = w_l row 0, row 1 = w_l row 1, bias at k=7
        half8 hy;
        #pragma unroll
        for (int j = 0; j < 8; ++j) {
            float v = 0.f;
            if (el < 2) {
                if (j < 5)                 v = w_l[el * HDIM + 4 * j + q];
                else if (j == 7 && q == 0) v = b_l[el];
            }
            hy[j] = (__fp16)v;
        }
        Ay = hy;
    }

    // constant word3 of the B fragment: halves (k=8q+6 -> 0, k=8q+7 -> bias)
    int w3const;
    {
        half2v c67; c67[0] = (__fp16)0.f; c67[1] = (__fp16)((q == 0) ? 1.f : 0.f);
        w3const = __builtin_bit_cast(int, c67);
    }

    // ---- state init: hprev fp32; Bf = own units packed (identity allgather) ----
    float hprev[5];
    half8 Bf;
    {
        const float* hb = hidden + (size_t)e * HDIM;
        #pragma unroll
        for (int T = 0; T < 5; ++T) hprev[T] = hb[4 * T + q];
        int4v bi;
        bi[0] = __builtin_bit_cast(int, __builtin_amdgcn_cvt_pkrtz(hprev[0], hprev[1]));
        bi[1] = __builtin_bit_cast(int, __builtin_amdgcn_cvt_pkrtz(hprev[2], hprev[3]));
        bi[2] = __builtin_bit_cast(int, __builtin_amdgcn_cvt_pkrtz(hprev[4], 0.f));
        bi[3] = w3const;
        Bf = __builtin_bit_cast(half8, bi);
    }

    const float4v czero = {0.f, 0.f, 0.f, 0.f};
    // Gate-MFMA C init: +4096 centers the LUT index, +0.5 makes the later
    // (int) truncation a round-to-nearest. nH slot stays 0 (it is added into
    // the tanh index via fma with r).
    const float4v cinit = {4096.5f, 4096.5f, 0.f, 0.f};
    float4v C[5];

    auto issue_gates = [&](const half8* A) {
        float4v ci = cinit;
        ci[2] = 4096.5f;                          // nI slot also pre-offset
        #pragma unroll
        for (int T = 0; T < 5; ++T) C[T] = mfma16(A[T], Bf, ci);
    };

    // nearest-entry LUT read; u already in [index] units with +4096.5 baked in
    auto lk = [&](const float* lut, float u) -> float {
        u = fminf(fmaxf(u, 0.f), 8191.f);
        return lut[(int)u];
    };

    auto finish_update = [&]() {
        // S1: r,z sigmoid lookups (10 independent reads)
        float rr_[5], zz[5];
        #pragma unroll
        for (int T = 0; T < 5; ++T) {
            rr_[T] = lk(lutS, C[T][0]);
            zz[T]  = lk(lutS, C[T][1]);
        }
        // S2: n tanh lookups (5 reads); C2 pre-offset, C3 raw (scaled nH)
        #pragma unroll
        for (int T = 0; T < 5; ++T) {
            float n = lk(lutT, __builtin_fmaf(rr_[T], C[T][3], C[T][2]));
            hprev[T] = __builtin_fmaf(zz[T], hprev[T] - n, n);   // (1-z)*n + z*h
        }
        // rebuild B fragment from own registers — no shuffles
        int4v bi;
        bi[0] = __builtin_bit_cast(int, __builtin_amdgcn_cvt_pkrtz(hprev[0], hprev[1]));
        bi[1] = __builtin_bit_cast(int, __builtin_amdgcn_cvt_pkrtz(hprev[2], hprev[3]));
        bi[2] = __builtin_bit_cast(int, __builtin_amdgcn_cvt_pkrtz(hprev[4], 0.f));
        bi[3] = w3const;
        Bf = __builtin_bit_cast(half8, bi);
    };

    float* outp = out + (size_t)e * 2 * step;

    // step 0 (x = 0): h_0 -> h_1
    issue_gates(Azero);
    finish_update();

    if ((step & 1) || step < 4) {
        // generic fallback (odd / tiny step) — simple schedule, float2 stores
        for (int t = 1; t < step; ++t) {
            issue_gates(Afold);
            float4v cy = mfma16(Ay, Bf, czero);
            if (q == 0) {
                float2 st; st.x = cy[0]; st.y = cy[1];
                *(float2*)(outp + 2 * (step - t)) = st;
            }
            finish_update();
        }
        float4v cy = mfma16(Ay, Bf, czero);
        if (q == 0) {
            float2 st; st.x = cy[0]; st.y = cy[1];
            *(float2*)(outp) = st;
        }
        return;
    }

    // ---- pipelined main path (even step >= 4) ----
    // output idx k is y from h_{step-k}; pairs (k, k-1) with k odd -> 16B store.
    float4v pend;          // {y_{k-1}.x, y_{k-1}.y, y_k.x, y_k.y} of previous pair
    float*  pendp;         // its (16B-aligned) destination

    {   // first pair: k0 = step-1
        issue_gates(Afold);
        float4v cyA = mfma16(Ay, Bf, czero);      // idx step-1
        finish_update();
        issue_gates(Afold);
        float4v cyB = mfma16(Ay, Bf, czero);      // idx step-2
        finish_update();                          // cyB completes under this
        pend[0] = cyB[0]; pend[1] = cyB[1]; pend[2] = cyA[0]; pend[3] = cyA[1];
        pendp = outp + 2 * (step - 2);
    }

    for (int k = step - 3; k >= 3; k -= 2) {
        issue_gates(Afold);
        float4v cyA = mfma16(Ay, Bf, czero);      // idx k
        if (q == 0) *(float4v*)pendp = pend;      // prev pair: data long ready
        finish_update();
        issue_gates(Afold);
        float4v cyB = mfma16(Ay, Bf, czero);      // idx k-1
        finish_update();
        pend[0] = cyB[0]; pend[1] = cyB[1]; pend[2] = cyA[0]; pend[3] = cyA[1];
        pendp = outp + 2 * (k - 1);
    }

    {   // last pair: k == 1
        issue_gates(Afold);
        float4v cyA = mfma16(Ay, Bf, czero);      // idx 1
        if (q == 0) *(float4v*)pendp = pend;
        finish_update();                          // Bf = h_step
        float4v cyB = mfma16(Ay, Bf, czero);      // idx 0
        if (q == 0) {
            float4v st; st[0] = cyB[0]; st[1] = cyB[1]; st[2] = cyA[0]; st[3] = cyA[1];
            *(float4v*)outp = st;
        }
    }
}

extern "C" void kernel_launch(void* const* d_in, const int* in_sizes, int n_in,
                              void* d_out, int out_size, void* d_ws, size_t ws_size,
                              hipStream_t stream) {
    const float* hidden = (const float*)d_in[0];
    const float* w_ih   = (const float*)d_in[1];
    const float* w_hh   = (const float*)d_in[2];
    const float* b_ih   = (const float*)d_in[3];
    const float* b_hh   = (const float*)d_in[4];
    const float* w_l    = (const float*)d_in[5];
    const float* b_l    = (const float*)d_in[6];
    const int*   step   = (const int*)d_in[7];
    float* out = (float*)d_out;

    int B = in_sizes[0] / HDIM;     // hidden is (1, B, 20); B = 32768
    int grid = B / 64;              // 4 waves/block x 16 elements/wave

    gru_decoder_kernel<<<grid, BLOCK, 0, stream>>>(
        hidden, w_ih, w_hh, b_ih, b_hh, w_l, b_l, step, out, B);
}

// Round 8
// 158.827 us; speedup vs baseline: 1.1206x; 1.0255x over previous
//
#include <hip/hip_runtime.h>

#define HDIM 20
#define BLOCK 256

typedef __fp16 half8 __attribute__((ext_vector_type(8)));
typedef __fp16 half2v __attribute__((ext_vector_type(2)));
typedef float  float4v __attribute__((ext_vector_type(4)));
typedef int    int4v  __attribute__((ext_vector_type(4)));

static __device__ __forceinline__ float4v mfma16(half8 a, half8 b, float4v c) {
    return __builtin_amdgcn_mfma_f32_16x16x32_f16(a, b, c, 0, 0, 0);
}

// KEY INVARIANT (unchanged since v2):
//   B-row permutation: k = 8q + i  <->  hidden unit 4i + q   (i<5; i=5,6 pad; k=7(q=0) bias=1).
//   C/D layout (m89): lane (q,el) holds D rows 4q..4q+3 of column el.
//   A rows: tile T, row 4q'+g = unit 4T+q', gate g in {r,z,nI,nH} -> lane (q,el)
//   computes h_new for exactly its own B rows. Pack own h to fp16, done.
//
// v9: HYBRID chain+issue cut. v8 evidence: VALU-busy fell 147 cyc/step but
// duration only 42 -> duration = max(issue, per-wave serial chain), and v8
// lengthened the chain (2 serial LDS reads: sigma_r -> tanh). Changes:
//  - r back to trans (exp2+rcp, ~40 cyc dep) -- removes one LDS latency from
//    the serial path; z + tanh stay LUT (z = pure prefetch, issued right
//    after MFMA, consumed last; tanh = the single remaining LDS on path).
//  - lean lookups: fmed3 clamp + cvt + and~3; x4 byte-scale folded into
//    A-scale (2048); +16384+2 center/round folded into MFMA C-input; tanh
//    table base folded into ds_read offset:32768 immediate. 3 VALU + 1 ds
//    per lookup (v8: 5 + 1).
//  - s_setprio(1) around gate-MFMA issue (T5 probe, removable).

__global__ __launch_bounds__(BLOCK, 2) void gru_decoder_kernel(
    const float* __restrict__ hidden,
    const float* __restrict__ w_ih,
    const float* __restrict__ w_hh,
    const float* __restrict__ b_ih,
    const float* __restrict__ b_hh,
    const float* __restrict__ w_l,
    const float* __restrict__ b_l,
    const int*  __restrict__ step_ptr,
    float* __restrict__ out,
    int B)
{
    __shared__ float lut[16384];   // [0,8192): sigmoid; [8192,16384): tanh; x=(i-4096)/512

    const int tid = threadIdx.x;

    // ---- build LUTs (once per block; same primitives as the old per-step path) ----
    for (int i = tid; i < 8192; i += BLOCK) {
        float x = (i - 4096) * (1.0f / 512.0f);
        float es = __builtin_amdgcn_exp2f(-1.4426950408889634f * x);
        lut[i] = __builtin_amdgcn_rcpf(1.f + es);                               // sigmoid(x)
        float et = __builtin_amdgcn_exp2f(2.8853900817779268f * x);
        lut[8192 + i] = __builtin_fmaf(-2.f, __builtin_amdgcn_rcpf(1.f + et), 1.f); // tanh(x)
    }
    __syncthreads();

    const int l   = tid & 63;
    const int wv  = tid >> 6;
    const int el  = l & 15;
    const int q   = l >> 4;
    const int e   = (blockIdx.x * 4 + wv) * 16 + el;
    const int step = *step_ptr;

    const float NL2E  = -1.4426950408889634f;   // r rows: exp2 path
    const float BSCALE = 2048.0f;               // z,nI,nH rows: byte-index units (512 idx * 4B)

    // ---- A fragments (once). Lane holds k=8q..8q+7; A row m=el of tile T is
    // unit 4T+(el>>2), gate type el&3 {0:r,1:z,2:nI,3:nH}. ----
    const int u_dst = el >> 2;
    const int g     = el & 3;

    half8 Afold[5], Azero[5], Ay;
    #pragma unroll
    for (int T = 0; T < 5; ++T) {
        const int u  = 4 * T + u_dst;
        const int rr = (g == 0) ? u : (g == 1) ? 20 + u : 40 + u;
        const float sc = (g == 0) ? NL2E : BSCALE;
        half8 hf, h0;
        #pragma unroll
        for (int j = 0; j < 8; ++j) {
            float af = 0.f, a0 = 0.f;
            if (j < 5) {
                const int uk = 4 * j + q;                 // permuted source unit
                float wx = w_ih[rr * 2 + 0] * w_l[uk] + w_ih[rr * 2 + 1] * w_l[HDIM + uk];
                float wh = w_hh[rr * HDIM + uk];
                if (g <= 1)      { af = wh + wx; a0 = wh; }
                else if (g == 2) { af = wx;      a0 = 0.f; }
                else             { af = wh;      a0 = wh; }
            } else if (j == 7 && q == 0) {                // bias column
                float bx = w_ih[rr * 2 + 0] * b_l[0] + w_ih[rr * 2 + 1] * b_l[1];
                if (g <= 1)      { af = b_ih[rr] + b_hh[rr] + bx; a0 = b_ih[rr] + b_hh[rr]; }
                else if (g == 2) { af = b_ih[rr] + bx;            a0 = b_ih[rr]; }
                else             { af = b_hh[rr];                 a0 = b_hh[rr]; }
            }
            hf[j] = (__fp16)(af * sc);
            h0[j] = (__fp16)(a0 * sc);
        }
        Afold[T] = hf;
        Azero[T] = h0;
    }
    {   // y tile (unscaled): row 0 = w_l row 0, row 1 = w_l row 1, bias at k=7
        half8 hy;
        #pragma unroll
        for (int j = 0; j < 8; ++j) {
            float v = 0.f;
            if (el < 2) {
                if (j < 5)                 v = w_l[el * HDIM + 4 * j + q];
                else if (j == 7 && q == 0) v = b_l[el];
            }
            hy[j] = (__fp16)v;
        }
        Ay = hy;
    }

    // constant word3 of the B fragment: halves (k=8q+6 -> 0, k=8q+7 -> bias)
    int w3const;
    {
        half2v c67; c67[0] = (__fp16)0.f; c67[1] = (__fp16)((q == 0) ? 1.f : 0.f);
        w3const = __builtin_bit_cast(int, c67);
    }

    // ---- state init ----
    float hprev[5];
    half8 Bf;
    {
        const float* hb = hidden + (size_t)e * HDIM;
        #pragma unroll
        for (int T = 0; T < 5; ++T) hprev[T] = hb[4 * T + q];
        int4v bi;
        bi[0] = __builtin_bit_cast(int, __builtin_amdgcn_cvt_pkrtz(hprev[0], hprev[1]));
        bi[1] = __builtin_bit_cast(int, __builtin_amdgcn_cvt_pkrtz(hprev[2], hprev[3]));
        bi[2] = __builtin_bit_cast(int, __builtin_amdgcn_cvt_pkrtz(hprev[4], 0.f));
        bi[3] = w3const;
        Bf = __builtin_bit_cast(half8, bi);
    }

    const float4v czero = {0.f, 0.f, 0.f, 0.f};
    // C-init: slot1 (z) and slot2 (nI) carry the byte-offset center 4*4096
    // plus +2 so that ((int)u) & ~3 rounds to the nearest table entry.
    const float4v cinit = {0.f, 16386.f, 16386.f, 0.f};
    const float  CLMAX = 32764.0f;              // clamp max (SGPR), table top entry
    float4v C[5];

    auto issue_gates = [&](const half8* A) {
        __builtin_amdgcn_s_setprio(1);
        #pragma unroll
        for (int T = 0; T < 5; ++T) C[T] = mfma16(A[T], Bf, cinit);
        __builtin_amdgcn_s_setprio(0);
    };

    const char* lbase = (const char*)lut;

    auto finish_update = [&]() {
        // z lookups FIRST (issued right after MFMA; results consumed last)
        float zz[5];
        #pragma unroll
        for (int T = 0; T < 5; ++T) {
            int bo = ((int)__builtin_amdgcn_fmed3f(C[T][1], 0.f, CLMAX)) & ~3;
            zz[T] = *(const float*)(lbase + bo);
        }
        // r via trans (short dep-latency; on the serial path)
        float rr_[5];
        #pragma unroll
        for (int T = 0; T < 5; ++T)
            rr_[T] = __builtin_amdgcn_rcpf(1.f + __builtin_amdgcn_exp2f(C[T][0]));
        // tanh lookups (single LDS latency on the path)
        float nn[5];
        #pragma unroll
        for (int T = 0; T < 5; ++T) {
            float ui = __builtin_fmaf(rr_[T], C[T][3], C[T][2]);
            int bo = ((int)__builtin_amdgcn_fmed3f(ui, 0.f, CLMAX)) & ~3;
            nn[T] = *(const float*)(lbase + 32768 + bo);
        }
        // blends + pack
        #pragma unroll
        for (int T = 0; T < 5; ++T)
            hprev[T] = __builtin_fmaf(zz[T], hprev[T] - nn[T], nn[T]);  // (1-z)*n + z*h
        int4v bi;
        bi[0] = __builtin_bit_cast(int, __builtin_amdgcn_cvt_pkrtz(hprev[0], hprev[1]));
        bi[1] = __builtin_bit_cast(int, __builtin_amdgcn_cvt_pkrtz(hprev[2], hprev[3]));
        bi[2] = __builtin_bit_cast(int, __builtin_amdgcn_cvt_pkrtz(hprev[4], 0.f));
        bi[3] = w3const;
        Bf = __builtin_bit_cast(half8, bi);
    };

    float* outp = out + (size_t)e * 2 * step;

    // step 0 (x = 0): h_0 -> h_1
    issue_gates(Azero);
    finish_update();

    if ((step & 1) || step < 4) {
        // generic fallback (odd / tiny step)
        for (int t = 1; t < step; ++t) {
            issue_gates(Afold);
            float4v cy = mfma16(Ay, Bf, czero);
            if (q == 0) {
                float2 st; st.x = cy[0]; st.y = cy[1];
                *(float2*)(outp + 2 * (step - t)) = st;
            }
            finish_update();
        }
        float4v cy = mfma16(Ay, Bf, czero);
        if (q == 0) {
            float2 st; st.x = cy[0]; st.y = cy[1];
            *(float2*)(outp) = st;
        }
        return;
    }

    // ---- pipelined main path (even step >= 4) ----
    float4v pend;          // {y_{k-1}.x, y_{k-1}.y, y_k.x, y_k.y} of previous pair
    float*  pendp;

    {   // first pair: k0 = step-1
        issue_gates(Afold);
        float4v cyA = mfma16(Ay, Bf, czero);      // idx step-1
        finish_update();
        issue_gates(Afold);
        float4v cyB = mfma16(Ay, Bf, czero);      // idx step-2
        finish_update();
        pend[0] = cyB[0]; pend[1] = cyB[1]; pend[2] = cyA[0]; pend[3] = cyA[1];
        pendp = outp + 2 * (step - 2);
    }

    for (int k = step - 3; k >= 3; k -= 2) {
        issue_gates(Afold);
        float4v cyA = mfma16(Ay, Bf, czero);      // idx k
        if (q == 0) *(float4v*)pendp = pend;      // prev pair: data long ready
        finish_update();
        issue_gates(Afold);
        float4v cyB = mfma16(Ay, Bf, czero);      // idx k-1
        finish_update();
        pend[0] = cyB[0]; pend[1] = cyB[1]; pend[2] = cyA[0]; pend[3] = cyA[1];
        pendp = outp + 2 * (k - 1);
    }

    {   // last pair: k == 1
        issue_gates(Afold);
        float4v cyA = mfma16(Ay, Bf, czero);      // idx 1
        if (q == 0) *(float4v*)pendp = pend;
        finish_update();                          // Bf = h_step
        float4v cyB = mfma16(Ay, Bf, czero);      // idx 0
        if (q == 0) {
            float4v st; st[0] = cyB[0]; st[1] = cyB[1]; st[2] = cyA[0]; st[3] = cyA[1];
            *(float4v*)outp = st;
        }
    }
}

extern "C" void kernel_launch(void* const* d_in, const int* in_sizes, int n_in,
                              void* d_out, int out_size, void* d_ws, size_t ws_size,
                              hipStream_t stream) {
    const float* hidden = (const float*)d_in[0];
    const float* w_ih   = (const float*)d_in[1];
    const float* w_hh   = (const float*)d_in[2];
    const float* b_ih   = (const float*)d_in[3];
    const float* b_hh   = (const float*)d_in[4];
    const float* w_l    = (const float*)d_in[5];
    const float* b_l    = (const float*)d_in[6];
    const int*   step   = (const int*)d_in[7];
    float* out = (float*)d_out;

    int B = in_sizes[0] / HDIM;     // hidden is (1, B, 20); B = 32768
    int grid = B / 64;              // 4 waves/block x 16 elements/wave

    gru_decoder_kernel<<<grid, BLOCK, 0, stream>>>(
        hidden, w_ih, w_hh, b_ih, b_hh, w_l, b_l, step, out, B);
}

// Round 9
// 157.806 us; speedup vs baseline: 1.1278x; 1.0065x over previous
//
#include <hip/hip_runtime.h>

#define HDIM 20
#define BLOCK 256

typedef __fp16 half8 __attribute__((ext_vector_type(8)));
typedef __fp16 half2v __attribute__((ext_vector_type(2)));
typedef float  float4v __attribute__((ext_vector_type(4)));
typedef int    int4v  __attribute__((ext_vector_type(4)));

static __device__ __forceinline__ float4v mfma16(half8 a, half8 b, float4v c) {
    return __builtin_amdgcn_mfma_f32_16x16x32_f16(a, b, c, 0, 0, 0);
}

// KEY INVARIANT (unchanged since v2):
//   B-row permutation: k = 8q + i  <->  hidden unit 4i + q   (i<5; i=5,6 pad; k=7(q=0) bias=1).
//   C/D layout (m89): lane (q,el) holds D rows 4q..4q+3 of column el.
//   A rows: tile T, row 4q'+g = unit 4T+q', gate g in {r,z,nI,nH} -> lane (q,el)
//   computes h_new for exactly its own B rows. Pack own h to fp16, done.
//
// v10 = v9 + one-time half-step wave de-phase. v9 evidence: idle ~276
// cyc/SIMD-step concentrated in the per-step lgkmcnt wait on the 5 tanh
// ds_reads (~120-140 cyc/wave-step). The 2 co-resident waves (blocks b and
// b+256 share a CU slot; 512 blocks over 256 CUs) run identical code in
// lockstep and stall TOGETHER. s_sleep(5) (~320 cyc ~ half a step) for the
// bit-8 partner anti-phases them so one wave's VALU/trans work covers the
// other's LDS wait. v6's null stagger is consistent: the all-trans kernel
// had only ~85 cyc/SIMD-step of idle -- nothing to recover then.
//
// v9 recap (kept): r via trans (exp2+rcp, short dep chain); z via LUT
// (pure prefetch: issued right after MFMA, consumed last); tanh via LUT
// (single LDS latency on the serial path); lean lookups (fmed3 clamp, x4
// byte-scale folded into A-scale 2048, +16384+2 center/round folded into
// MFMA C-input, tanh base as +32768 addr offset); s_setprio around MFMA.

__global__ __launch_bounds__(BLOCK, 2) void gru_decoder_kernel(
    const float* __restrict__ hidden,
    const float* __restrict__ w_ih,
    const float* __restrict__ w_hh,
    const float* __restrict__ b_ih,
    const float* __restrict__ b_hh,
    const float* __restrict__ w_l,
    const float* __restrict__ b_l,
    const int*  __restrict__ step_ptr,
    float* __restrict__ out,
    int B)
{
    __shared__ float lut[16384];   // [0,8192): sigmoid; [8192,16384): tanh; x=(i-4096)/512

    const int tid = threadIdx.x;

    // ---- build LUTs (once per block; same primitives as the old per-step path) ----
    for (int i = tid; i < 8192; i += BLOCK) {
        float x = (i - 4096) * (1.0f / 512.0f);
        float es = __builtin_amdgcn_exp2f(-1.4426950408889634f * x);
        lut[i] = __builtin_amdgcn_rcpf(1.f + es);                               // sigmoid(x)
        float et = __builtin_amdgcn_exp2f(2.8853900817779268f * x);
        lut[8192 + i] = __builtin_fmaf(-2.f, __builtin_amdgcn_rcpf(1.f + et), 1.f); // tanh(x)
    }
    __syncthreads();

    const int l   = tid & 63;
    const int wv  = tid >> 6;
    const int el  = l & 15;
    const int q   = l >> 4;
    const int e   = (blockIdx.x * 4 + wv) * 16 + el;
    const int step = *step_ptr;

    const float NL2E  = -1.4426950408889634f;   // r rows: exp2 path
    const float BSCALE = 2048.0f;               // z,nI,nH rows: byte-index units (512 idx * 4B)

    // ---- A fragments (once). Lane holds k=8q..8q+7; A row m=el of tile T is
    // unit 4T+(el>>2), gate type el&3 {0:r,1:z,2:nI,3:nH}. ----
    const int u_dst = el >> 2;
    const int g     = el & 3;

    half8 Afold[5], Azero[5], Ay;
    #pragma unroll
    for (int T = 0; T < 5; ++T) {
        const int u  = 4 * T + u_dst;
        const int rr = (g == 0) ? u : (g == 1) ? 20 + u : 40 + u;
        const float sc = (g == 0) ? NL2E : BSCALE;
        half8 hf, h0;
        #pragma unroll
        for (int j = 0; j < 8; ++j) {
            float af = 0.f, a0 = 0.f;
            if (j < 5) {
                const int uk = 4 * j + q;                 // permuted source unit
                float wx = w_ih[rr * 2 + 0] * w_l[uk] + w_ih[rr * 2 + 1] * w_l[HDIM + uk];
                float wh = w_hh[rr * HDIM + uk];
                if (g <= 1)      { af = wh + wx; a0 = wh; }
                else if (g == 2) { af = wx;      a0 = 0.f; }
                else             { af = wh;      a0 = wh; }
            } else if (j == 7 && q == 0) {                // bias column
                float bx = w_ih[rr * 2 + 0] * b_l[0] + w_ih[rr * 2 + 1] * b_l[1];
                if (g <= 1)      { af = b_ih[rr] + b_hh[rr] + bx; a0 = b_ih[rr] + b_hh[rr]; }
                else if (g == 2) { af = b_ih[rr] + bx;            a0 = b_ih[rr]; }
                else             { af = b_hh[rr];                 a0 = b_hh[rr]; }
            }
            hf[j] = (__fp16)(af * sc);
            h0[j] = (__fp16)(a0 * sc);
        }
        Afold[T] = hf;
        Azero[T] = h0;
    }
    {   // y tile (unscaled): row 0 = w_l row 0, row 1 = w_l row 1, bias at k=7
        half8 hy;
        #pragma unroll
        for (int j = 0; j < 8; ++j) {
            float v = 0.f;
            if (el < 2) {
                if (j < 5)                 v = w_l[el * HDIM + 4 * j + q];
                else if (j == 7 && q == 0) v = b_l[el];
            }
            hy[j] = (__fp16)v;
        }
        Ay = hy;
    }

    // constant word3 of the B fragment: halves (k=8q+6 -> 0, k=8q+7 -> bias)
    int w3const;
    {
        half2v c67; c67[0] = (__fp16)0.f; c67[1] = (__fp16)((q == 0) ? 1.f : 0.f);
        w3const = __builtin_bit_cast(int, c67);
    }

    // ---- state init ----
    float hprev[5];
    half8 Bf;
    {
        const float* hb = hidden + (size_t)e * HDIM;
        #pragma unroll
        for (int T = 0; T < 5; ++T) hprev[T] = hb[4 * T + q];
        int4v bi;
        bi[0] = __builtin_bit_cast(int, __builtin_amdgcn_cvt_pkrtz(hprev[0], hprev[1]));
        bi[1] = __builtin_bit_cast(int, __builtin_amdgcn_cvt_pkrtz(hprev[2], hprev[3]));
        bi[2] = __builtin_bit_cast(int, __builtin_amdgcn_cvt_pkrtz(hprev[4], 0.f));
        bi[3] = w3const;
        Bf = __builtin_bit_cast(half8, bi);
    }

    const float4v czero = {0.f, 0.f, 0.f, 0.f};
    // C-init: slot1 (z) and slot2 (nI) carry the byte-offset center 4*4096
    // plus +2 so that ((int)u) & ~3 rounds to the nearest table entry.
    const float4v cinit = {0.f, 16386.f, 16386.f, 0.f};
    const float  CLMAX = 32764.0f;              // clamp max (SGPR), table top entry
    float4v C[5];

    auto issue_gates = [&](const half8* A) {
        __builtin_amdgcn_s_setprio(1);
        #pragma unroll
        for (int T = 0; T < 5; ++T) C[T] = mfma16(A[T], Bf, cinit);
        __builtin_amdgcn_s_setprio(0);
    };

    const char* lbase = (const char*)lut;

    auto finish_update = [&]() {
        // z lookups FIRST (issued right after MFMA; results consumed last)
        float zz[5];
        #pragma unroll
        for (int T = 0; T < 5; ++T) {
            int bo = ((int)__builtin_amdgcn_fmed3f(C[T][1], 0.f, CLMAX)) & ~3;
            zz[T] = *(const float*)(lbase + bo);
        }
        // r via trans (short dep-latency; on the serial path)
        float rr_[5];
        #pragma unroll
        for (int T = 0; T < 5; ++T)
            rr_[T] = __builtin_amdgcn_rcpf(1.f + __builtin_amdgcn_exp2f(C[T][0]));
        // tanh lookups (single LDS latency on the path)
        float nn[5];
        #pragma unroll
        for (int T = 0; T < 5; ++T) {
            float ui = __builtin_fmaf(rr_[T], C[T][3], C[T][2]);
            int bo = ((int)__builtin_amdgcn_fmed3f(ui, 0.f, CLMAX)) & ~3;
            nn[T] = *(const float*)(lbase + 32768 + bo);
        }
        // blends + pack
        #pragma unroll
        for (int T = 0; T < 5; ++T)
            hprev[T] = __builtin_fmaf(zz[T], hprev[T] - nn[T], nn[T]);  // (1-z)*n + z*h
        int4v bi;
        bi[0] = __builtin_bit_cast(int, __builtin_amdgcn_cvt_pkrtz(hprev[0], hprev[1]));
        bi[1] = __builtin_bit_cast(int, __builtin_amdgcn_cvt_pkrtz(hprev[2], hprev[3]));
        bi[2] = __builtin_bit_cast(int, __builtin_amdgcn_cvt_pkrtz(hprev[4], 0.f));
        bi[3] = w3const;
        Bf = __builtin_bit_cast(half8, bi);
    };

    float* outp = out + (size_t)e * 2 * step;

    // One-time anti-phase of the two co-resident waves per SIMD (~320 cyc ~
    // half a step). Co-resident blocks on a CU are (b, b+256): bit 8.
    // Placed AFTER the LUT-build barrier so it isn't absorbed by __syncthreads.
    if ((blockIdx.x >> 8) & 1) __builtin_amdgcn_s_sleep(5);

    // step 0 (x = 0): h_0 -> h_1
    issue_gates(Azero);
    finish_update();

    if ((step & 1) || step < 4) {
        // generic fallback (odd / tiny step)
        for (int t = 1; t < step; ++t) {
            issue_gates(Afold);
            float4v cy = mfma16(Ay, Bf, czero);
            if (q == 0) {
                float2 st; st.x = cy[0]; st.y = cy[1];
                *(float2*)(outp + 2 * (step - t)) = st;
            }
            finish_update();
        }
        float4v cy = mfma16(Ay, Bf, czero);
        if (q == 0) {
            float2 st; st.x = cy[0]; st.y = cy[1];
            *(float2*)(outp) = st;
        }
        return;
    }

    // ---- pipelined main path (even step >= 4) ----
    float4v pend;          // {y_{k-1}.x, y_{k-1}.y, y_k.x, y_k.y} of previous pair
    float*  pendp;

    {   // first pair: k0 = step-1
        issue_gates(Afold);
        float4v cyA = mfma16(Ay, Bf, czero);      // idx step-1
        finish_update();
        issue_gates(Afold);
        float4v cyB = mfma16(Ay, Bf, czero);      // idx step-2
        finish_update();
        pend[0] = cyB[0]; pend[1] = cyB[1]; pend[2] = cyA[0]; pend[3] = cyA[1];
        pendp = outp + 2 * (step - 2);
    }

    for (int k = step - 3; k >= 3; k -= 2) {
        issue_gates(Afold);
        float4v cyA = mfma16(Ay, Bf, czero);      // idx k
        if (q == 0) *(float4v*)pendp = pend;      // prev pair: data long ready
        finish_update();
        issue_gates(Afold);
        float4v cyB = mfma16(Ay, Bf, czero);      // idx k-1
        finish_update();
        pend[0] = cyB[0]; pend[1] = cyB[1]; pend[2] = cyA[0]; pend[3] = cyA[1];
        pendp = outp + 2 * (k - 1);
    }

    {   // last pair: k == 1
        issue_gates(Afold);
        float4v cyA = mfma16(Ay, Bf, czero);      // idx 1
        if (q == 0) *(float4v*)pendp = pend;
        finish_update();                          // Bf = h_step
        float4v cyB = mfma16(Ay, Bf, czero);      // idx 0
        if (q == 0) {
            float4v st; st[0] = cyB[0]; st[1] = cyB[1]; st[2] = cyA[0]; st[3] = cyA[1];
            *(float4v*)outp = st;
        }
    }
}

extern "C" void kernel_launch(void* const* d_in, const int* in_sizes, int n_in,
                              void* d_out, int out_size, void* d_ws, size_t ws_size,
                              hipStream_t stream) {
    const float* hidden = (const float*)d_in[0];
    const float* w_ih   = (const float*)d_in[1];
    const float* w_hh   = (const float*)d_in[2];
    const float* b_ih   = (const float*)d_in[3];
    const float* b_hh   = (const float*)d_in[4];
    const float* w_l    = (const float*)d_in[5];
    const float* b_l    = (const float*)d_in[6];
    const int*   step   = (const int*)d_in[7];
    float* out = (float*)d_out;

    int B = in_sizes[0] / HDIM;     // hidden is (1, B, 20); B = 32768
    int grid = B / 64;              // 4 waves/block x 16 elements/wave

    gru_decoder_kernel<<<grid, BLOCK, 0, stream>>>(
        hidden, w_ih, w_hh, b_ih, b_hh, w_l, b_l, step, out, B);
}